// Round 10
// baseline (1185.752 us; speedup 1.0000x reference)
//
#include <hip/hip_runtime.h>

#define NUU 100000
#define NII 50000
#define NEDGE 500000
#define NROWS (NII + NUU)          // combined CSR row count (items first, then users)

typedef float f32x4 __attribute__((ext_vector_type(4)));
typedef short bf16x8 __attribute__((ext_vector_type(8)));
typedef _Float16 half8v __attribute__((ext_vector_type(8)));
typedef _Float16 half4v __attribute__((ext_vector_type(4)));

// Two-problem GEMM: out = A1@W1 (+ A2@W2) + bias, mode 0=none 1=relu 2=LN.
// A operands fp32 (a16=0) or fp16 (a16=1; split-bf16 is EXACT on fp16 inputs).
// W pre-split frag-ordered bf16 hi/lo planes. In-place A==out / A2==out16 is SAFE:
// each wave reads only its own 64-row slice before its epilogue stores, and no
// other block touches those rows.
struct GemmP {
    const void* A1; const unsigned short* Wh1; const unsigned short* Wl1;
    const void* A2; const unsigned short* Wh2; const unsigned short* Wl2;
    const float* bias; const float* lg; const float* lb;
    float* out; _Float16* out16; float* nrm; int M; int mode; int a16;
};

// Split-bf16 MFMA GEMM. Block = 256 thr = 4 waves; tile 256 rows; wave = 64 rows
// (4 m-tiles of 16). Computes D = W^T h^T per 16x16x32 MFMA so each lane owns one
// output row with float4-contiguous columns. 3 MFMAs per tile-pair: hh + lh + hl.
__global__ __launch_bounds__(256, 3)
void gemm_dual(GemmP P0, GemmP P1, int gb0,
               const float* __restrict__ pw, const float* __restrict__ pb,
               const float* __restrict__ pu, float* __restrict__ pout)
{
    const bool sel = (blockIdx.x >= gb0);
    const GemmP P = sel ? P1 : P0;             // wave-uniform
    const int bi = sel ? (int)blockIdx.x - gb0 : (int)blockIdx.x;
    const int tid = threadIdx.x;
    const int l  = tid & 63;
    const int w  = tid >> 6;
    const int lm = l & 15;          // output row within 16-tile / W col
    const int lk = l >> 4;          // k-subgroup 0..3
    const int rowb = bi * 256 + w * 64;

    f32x4 acc[4][8];
#pragma unroll
    for (int mt = 0; mt < 4; ++mt)
#pragma unroll
        for (int nt = 0; nt < 8; ++nt) acc[mt][nt] = (f32x4){0.f, 0.f, 0.f, 0.f};

    const int nmat = (P.A2 != nullptr) ? 2 : 1;
    for (int m = 0; m < nmat; ++m) {
        const void* A = m ? P.A2 : P.A1;
        const unsigned short* Wh = m ? P.Wh2 : P.Wh1;
        const unsigned short* Wl = m ? P.Wl2 : P.Wl1;
#pragma unroll
        for (int kt = 0; kt < 4; ++kt) {
            // A-frags: lane reads 8 elems of row (rowb+mt*16+lm) at k = kt*32+lk*8,
            // exact-splits into bf16 hi/lo in registers.
            bf16x8 ah[4], al[4];
#pragma unroll
            for (int mt = 0; mt < 4; ++mt) {
                int row = rowb + mt * 16 + lm;
                int rowc = row < P.M ? row : P.M - 1;   // clamp: feeds only invalid rows
                float a8[8];
                if (P.a16) {
                    const _Float16* ap = (const _Float16*)A + (size_t)rowc * 128 + kt * 32 + lk * 8;
                    half8v hv = *(const half8v*)ap;
#pragma unroll
                    for (int j = 0; j < 8; ++j) a8[j] = (float)hv[j];
                } else {
                    const float* ap = (const float*)A + (size_t)rowc * 128 + kt * 32 + lk * 8;
                    float4 f0 = *(const float4*)ap;
                    float4 f1 = *(const float4*)(ap + 4);
                    a8[0] = f0.x; a8[1] = f0.y; a8[2] = f0.z; a8[3] = f0.w;
                    a8[4] = f1.x; a8[5] = f1.y; a8[6] = f1.z; a8[7] = f1.w;
                }
                union { bf16x8 v; unsigned int u[4]; } H, L;
#pragma unroll
                for (int p = 0; p < 4; ++p) {
                    unsigned int u0 = __float_as_uint(a8[2 * p]);
                    unsigned int u1 = __float_as_uint(a8[2 * p + 1]);
                    H.u[p] = (u0 >> 16) | (u1 & 0xffff0000u);
                    float l0 = a8[2 * p]     - __uint_as_float(u0 & 0xffff0000u);
                    float l1 = a8[2 * p + 1] - __uint_as_float(u1 & 0xffff0000u);
                    L.u[p] = (__float_as_uint(l0) >> 16) | (__float_as_uint(l1) & 0xffff0000u);
                }
                ah[mt] = H.v;
                al[mt] = L.v;
            }
            // B-frags (pre-split W planes) in two halves of 4 n-tiles to cap VGPRs
#pragma unroll
            for (int h = 0; h < 2; ++h) {
                bf16x8 bh[4], bl[4];
#pragma unroll
                for (int q = 0; q < 4; ++q) {
                    size_t fo = (size_t)((kt * 8 + h * 4 + q) * 64 + l) * 8;
                    bh[q] = *(const bf16x8*)(Wh + fo);
                    bl[q] = *(const bf16x8*)(Wl + fo);
                }
#pragma unroll
                for (int mt = 0; mt < 4; ++mt)
#pragma unroll
                    for (int q = 0; q < 4; ++q) {
                        int nt = h * 4 + q;
                        acc[mt][nt] = __builtin_amdgcn_mfma_f32_16x16x32_bf16(bh[q], ah[mt], acc[mt][nt], 0, 0, 0);
                        acc[mt][nt] = __builtin_amdgcn_mfma_f32_16x16x32_bf16(bl[q], ah[mt], acc[mt][nt], 0, 0, 0);
                        acc[mt][nt] = __builtin_amdgcn_mfma_f32_16x16x32_bf16(bh[q], al[mt], acc[mt][nt], 0, 0, 0);
                    }
            }
        }
    }

    // epilogue: lane holds row = rowb+mt*16+lm, col = nt*16+lk*4+i
    f32x4 bv[8];
#pragma unroll
    for (int nt = 0; nt < 8; ++nt)
        bv[nt] = *(const f32x4*)(P.bias + nt * 16 + lk * 4);

#pragma unroll
    for (int mt = 0; mt < 4; ++mt) {
        int row = rowb + mt * 16 + lm;
        bool valid = row < P.M;
        float v[8][4];
#pragma unroll
        for (int nt = 0; nt < 8; ++nt)
#pragma unroll
            for (int i = 0; i < 4; ++i) v[nt][i] = acc[mt][nt][i] + bv[nt][i];
        if (P.mode == 1) {
#pragma unroll
            for (int nt = 0; nt < 8; ++nt)
#pragma unroll
                for (int i = 0; i < 4; ++i) v[nt][i] = fmaxf(v[nt][i], 0.f);
        } else if (P.mode == 2) {
            float s = 0.f, sq = 0.f;
#pragma unroll
            for (int nt = 0; nt < 8; ++nt)
#pragma unroll
                for (int i = 0; i < 4; ++i) { s += v[nt][i]; sq += v[nt][i] * v[nt][i]; }
            s  += __shfl_xor(s, 16, 64);  s  += __shfl_xor(s, 32, 64);
            sq += __shfl_xor(sq, 16, 64); sq += __shfl_xor(sq, 32, 64);
            float mean = s * (1.f / 128.f);
            float var  = sq * (1.f / 128.f) - mean * mean;
            float inv  = rsqrtf(var + 1e-5f);
#pragma unroll
            for (int nt = 0; nt < 8; ++nt) {
                f32x4 lg = *(const f32x4*)(P.lg + nt * 16 + lk * 4);
                f32x4 lb = *(const f32x4*)(P.lb + nt * 16 + lk * 4);
#pragma unroll
                for (int i = 0; i < 4; ++i) v[nt][i] = (v[nt][i] - mean) * inv * lg[i] + lb[i];
            }
        }
        if (pout != nullptr) {      // fused 128->2 head + gumbel-hard (enc launch)
            float q0 = 0.f, q1 = 0.f;
#pragma unroll
            for (int nt = 0; nt < 8; ++nt) {
                const float* pp = pw + (size_t)(nt * 16 + lk * 4) * 2;
                f32x4 pa = *(const f32x4*)pp;
                f32x4 pc = *(const f32x4*)(pp + 4);
                q0 += v[nt][0] * pa[0] + v[nt][1] * pa[2] + v[nt][2] * pc[0] + v[nt][3] * pc[2];
                q1 += v[nt][0] * pa[1] + v[nt][1] * pa[3] + v[nt][2] * pc[1] + v[nt][3] * pc[3];
            }
            q0 += __shfl_xor(q0, 16, 64); q0 += __shfl_xor(q0, 32, 64);
            q1 += __shfl_xor(q1, 16, 64); q1 += __shfl_xor(q1, 32, 64);
            if (lk == 0 && valid) {
                float l0 = q0 + pb[0], l1 = q1 + pb[1];
                float u0 = pu[2 * row], u1 = pu[2 * row + 1];
                float g0 = -logf(-logf(u0 * (1.f - 2e-6f) + 1e-6f));
                float g1 = -logf(-logf(u1 * (1.f - 2e-6f) + 1e-6f));
                float z0 = l0 + g0, z1 = l1 + g1;   // TAU = 1.0
                float mz = fmaxf(z0, z1);
                float e0 = expf(z0 - mz), e1 = expf(z1 - mz);
                float y0 = e0 / (e0 + e1);
                pout[row] = (z0 >= z1) ? ((1.f - y0) + y0) : 0.f;  // fwd of (hard-y)+y
            }
        }
        if (P.nrm != nullptr) {     // fused row L2 norm (projection outputs)
            float sq = 0.f;
#pragma unroll
            for (int nt = 0; nt < 8; ++nt)
#pragma unroll
                for (int i = 0; i < 4; ++i) sq += v[nt][i] * v[nt][i];
            sq += __shfl_xor(sq, 16, 64); sq += __shfl_xor(sq, 32, 64);
            if (lk == 0 && valid) P.nrm[row] = fmaxf(sqrtf(sq), 1e-8f);
        }
        if (valid) {
            if (P.out != nullptr) {
#pragma unroll
                for (int nt = 0; nt < 8; ++nt)
                    *(float4*)(P.out + (size_t)row * 128 + nt * 16 + lk * 4) =
                        make_float4(v[nt][0], v[nt][1], v[nt][2], v[nt][3]);
            }
            if (P.out16 != nullptr) {   // fp16 copy for downstream gathers / next layer
#pragma unroll
                for (int nt = 0; nt < 8; ++nt) {
                    half4v h;
#pragma unroll
                    for (int i = 0; i < 4; ++i) h[i] = (_Float16)v[nt][i];
                    *(half4v*)(P.out16 + (size_t)row * 128 + nt * 16 + lk * 4) = h;
                }
            }
        }
    }
}

// ---- weight pre-split: 15 matrices [128][128] fp32 -> frag-ordered bf16 hi/lo planes
struct WSrc { const float* p[7]; };
__global__ void wsplit_k(WSrc S, unsigned short* __restrict__ wout)
{
    int gid = blockIdx.x * 256 + threadIdx.x;
    if (gid >= 15 * 16384) return;
    int m = gid >> 14;
    int idx = gid & 16383;
    int k = idx >> 7, n = idx & 127;
    const float* src;
    if (m == 0) src = S.p[0];
    else if (m == 1) src = S.p[1];
    else if (m == 2) src = S.p[2];
    else if (m < 6)  src = S.p[3] + (size_t)(m - 3) * 16384;
    else if (m < 9)  src = S.p[4] + (size_t)(m - 6) * 16384;
    else if (m < 12) src = S.p[5] + (size_t)(m - 9) * 16384;
    else             src = S.p[6] + (size_t)(m - 12) * 16384;
    float wv = src[idx];
    unsigned int u = __float_as_uint(wv);
    unsigned short hi = (unsigned short)(u >> 16);
    float lof = wv - __uint_as_float(u & 0xffff0000u);
    unsigned short lo = (unsigned short)(__float_as_uint(lof) >> 16);
    int kt = k >> 5, kr = k & 31;
    int dst = ((kt * 8 + (n >> 4)) * 64 + ((kr >> 3) * 16 + (n & 15))) * 8 + (kr & 7);
    unsigned short* wm = wout + (size_t)m * 32768;
    wm[dst] = hi;
    wm[dst + 16384] = lo;
}

// ------- structural contrastive loss (quarter-wave per edge, half8 fp16 gathers) -------
__global__ void loss_k(const _Float16* __restrict__ hu16, const _Float16* __restrict__ hi16,
                       const float* __restrict__ nu, const float* __restrict__ ni,
                       const int* __restrict__ src, const int* __restrict__ dst,
                       const int* __restrict__ uneg, const int* __restrict__ ineg,
                       float* __restrict__ loss, int ne)
{
    __shared__ float ls[4];
    int lane = threadIdx.x & 63;
    int q = lane >> 4;              // quarter id: which edge of the 4
    int c8 = (lane & 15) * 8;       // 16 lanes x 8 halves = 128 cols
    int wib = threadIdx.x >> 6;
    int gw = (blockIdx.x * blockDim.x + threadIdx.x) >> 6;
    int nw = (gridDim.x * blockDim.x) >> 6;
    float part = 0.f;
    for (int eb = gw; eb < ne / 4; eb += nw) {   // ne divisible by 4
        int e = eb * 4 + q;
        int s = src[e], d = dst[e], un = uneg[e], in_ = ineg[e];
        half8v a = *(const half8v*)(hu16 + (size_t)s * 128 + c8);
        half8v b = *(const half8v*)(hi16 + (size_t)d * 128 + c8);
        half8v c = *(const half8v*)(hi16 + (size_t)in_ * 128 + c8);
        half8v dd = *(const half8v*)(hu16 + (size_t)un * 128 + c8);
        float p_sd = 0.f, p_sn = 0.f, p_nd = 0.f;
#pragma unroll
        for (int j = 0; j < 8; ++j) {
            float af = (float)a[j], bf = (float)b[j];
            p_sd += af * bf;
            p_sn += af * (float)c[j];
            p_nd += (float)dd[j] * bf;
        }
#pragma unroll
        for (int m = 1; m < 16; m <<= 1) {        // reduce within quarter-wave
            p_sd += __shfl_xor(p_sd, m, 64);
            p_sn += __shfl_xor(p_sn, m, 64);
            p_nd += __shfl_xor(p_nd, m, 64);
        }
        if ((lane & 15) == 0) {
            float pos = p_sd / (nu[s] * ni[d]);
            float neg = p_sn / (nu[s] * ni[in_]) + p_nd / (nu[un] * ni[d]);
            float pe = expf(pos * 10.f);
            float nex = expf(neg * 10.f);
            part += -logf(pe / (pe + nex));
        }
    }
    part += __shfl_xor(part, 16, 64);
    part += __shfl_xor(part, 32, 64);
    if (lane == 0) ls[wib] = part;
    __syncthreads();
    if (threadIdx.x == 0)
        atomicAdd(loss, (ls[0] + ls[1] + ls[2] + ls[3]) * (1.f / 500000.f));
}

// ---------------- CSR build (combined item||user row space) ----------------
__global__ void hist2_k(const int* __restrict__ ui_dst, const int* __restrict__ iu_dst,
                        int* __restrict__ deg)
{
    int e = blockIdx.x * blockDim.x + threadIdx.x;
    if (e < NEDGE) atomicAdd(&deg[ui_dst[e]], 1);                         // item rows
    else if (e < 2 * NEDGE) atomicAdd(&deg[NII + iu_dst[e - NEDGE]], 1);  // user rows
}

// 3-phase parallel exclusive scan over NROWS entries
__global__ void scan_part_k(const int* __restrict__ in, int* __restrict__ part, int N)
{
    __shared__ int wsum[4];
    int base = blockIdx.x * 1024 + threadIdx.x * 4;
    int s = 0;
    if (base + 3 < N) {
        int4 v = *(const int4*)(in + base);
        s = v.x + v.y + v.z + v.w;
    } else {
#pragma unroll
        for (int j = 0; j < 4; ++j) if (base + j < N) s += in[base + j];
    }
#pragma unroll
    for (int m = 1; m < 64; m <<= 1) s += __shfl_xor(s, m, 64);
    if ((threadIdx.x & 63) == 0) wsum[threadIdx.x >> 6] = s;
    __syncthreads();
    if (threadIdx.x == 0) part[blockIdx.x] = wsum[0] + wsum[1] + wsum[2] + wsum[3];
}

__global__ void scan_top_k(int* __restrict__ p, int nb)
{
    __shared__ int sm[256];
    int t = threadIdx.x;
    int v = (t < nb) ? p[t] : 0;
    sm[t] = v;
    __syncthreads();
    for (int o = 1; o < 256; o <<= 1) {
        int x = (t >= o) ? sm[t - o] : 0;
        __syncthreads();
        sm[t] += x;
        __syncthreads();
    }
    if (t < nb) p[t] = sm[t] - v;   // exclusive
}

__global__ void scan_final_k(const int* __restrict__ in, const int* __restrict__ part,
                             int* __restrict__ out, int N, int total)
{
    __shared__ int wtot[4];
    int tid = threadIdx.x;
    int lane = tid & 63, wid = tid >> 6;
    int base = blockIdx.x * 1024 + tid * 4;
    int v[4] = {0, 0, 0, 0};
    bool full = (base + 3 < N);
    if (full) {
        int4 q = *(const int4*)(in + base);
        v[0] = q.x; v[1] = q.y; v[2] = q.z; v[3] = q.w;
    } else {
#pragma unroll
        for (int j = 0; j < 4; ++j) if (base + j < N) v[j] = in[base + j];
    }
    int s = v[0] + v[1] + v[2] + v[3];
    int incl = s;
#pragma unroll
    for (int o = 1; o < 64; o <<= 1) {
        int n = __shfl_up(incl, o, 64);
        if (lane >= o) incl += n;
    }
    if (lane == 63) wtot[wid] = incl;
    __syncthreads();
    int woff = 0;
    for (int w2 = 0; w2 < wid; ++w2) woff += wtot[w2];
    int run = part[blockIdx.x] + woff + incl - s;   // exclusive offset for v[0]
    if (full) {
        int4 o4 = make_int4(run, run + v[0], run + v[0] + v[1], run + v[0] + v[1] + v[2]);
        *(int4*)(out + base) = o4;
    } else {
#pragma unroll
        for (int j = 0; j < 4; ++j) {
            if (base + j < N) { out[base + j] = run; run += v[j]; }
        }
    }
    if (blockIdx.x == 0 && tid == 0) out[N] = total;
}

__global__ void fill2_k(const int* __restrict__ ui_dst, const int* __restrict__ ui_src,
                        const int* __restrict__ iu_dst, const int* __restrict__ iu_src,
                        const int* __restrict__ rowstart, int* __restrict__ cursor,
                        int* __restrict__ elist)
{
    int e = blockIdx.x * blockDim.x + threadIdx.x;
    if (e < NEDGE) {
        int d = ui_dst[e];
        int p = atomicAdd(&cursor[d], 1);
        elist[rowstart[d] + p] = ui_src[e];
    } else if (e < 2 * NEDGE) {
        int d = NII + iu_dst[e - NEDGE];
        int p = atomicAdd(&cursor[d], 1);
        elist[rowstart[d] + p] = iu_src[e - NEDGE];
    }
}

// --- combined CSR aggregation (wave per dest row, 4 edges in flight via quarter-
// waves, half8 fp16 gathers, fp32 accumulate, fp16 write). Items sum hu16 rows into
// ai16; users sum hi16 rows into au16.
__global__ void agg_dual(const _Float16* __restrict__ hu16, const _Float16* __restrict__ hi16,
                         const int* __restrict__ rowstart, const int* __restrict__ elist,
                         _Float16* __restrict__ ai16, _Float16* __restrict__ au16)
{
    int gt = blockIdx.x * blockDim.x + threadIdx.x;
    int w = gt >> 6, lane = gt & 63;
    if (w >= NROWS) return;
    const _Float16* src;
    _Float16* dst;
    if (w < NII) { src = hu16; dst = ai16 + (size_t)w * 128; }
    else         { src = hi16; dst = au16 + (size_t)(w - NII) * 128; }
    int q = lane >> 4;
    int c8 = (lane & 15) * 8;
    int s0 = rowstart[w], s1 = rowstart[w + 1];
    float a[8] = {0.f, 0.f, 0.f, 0.f, 0.f, 0.f, 0.f, 0.f};
    for (int e = s0 + q; e < s1; e += 4) {
        int s = elist[e];
        half8v v = *(const half8v*)(src + (size_t)s * 128 + c8);
#pragma unroll
        for (int j = 0; j < 8; ++j) a[j] += (float)v[j];
    }
#pragma unroll
    for (int j = 0; j < 8; ++j) {
        a[j] += __shfl_xor(a[j], 16, 64);
        a[j] += __shfl_xor(a[j], 32, 64);
    }
    if (lane < 16) {
        half8v o;
#pragma unroll
        for (int j = 0; j < 8; ++j) o[j] = (_Float16)a[j];
        *(half8v*)(dst + c8) = o;
    }
}

extern "C" void kernel_launch(void* const* d_in, const int* in_sizes, int n_in,
                              void* d_out, int out_size, void* d_ws, size_t ws_size,
                              hipStream_t stream)
{
    const float* x_user  = (const float*)d_in[0];
    const float* x_item  = (const float*)d_in[1];
    const float* u_user  = (const float*)d_in[3];
    const float* Wu_proj = (const float*)d_in[5];
    const float* bu_proj = (const float*)d_in[6];
    const float* Wi_proj = (const float*)d_in[7];
    const float* bi_proj = (const float*)d_in[8];
    const float* Wu_enc  = (const float*)d_in[9];
    const float* bu_enc  = (const float*)d_in[10];
    const float* Wu_act  = (const float*)d_in[11];
    const float* bu_act  = (const float*)d_in[12];
    // d_in[2,4,13..16] (item_pop, u_item, FairItemNet) are dead code in the reference
    const float* Wl_ui = (const float*)d_in[17];
    const float* Wr_ui = (const float*)d_in[18];
    const float* b_ui  = (const float*)d_in[19];
    const float* Wl_iu = (const float*)d_in[20];
    const float* Wr_iu = (const float*)d_in[21];
    const float* b_iu  = (const float*)d_in[22];
    const float* ln_u_g = (const float*)d_in[23];
    const float* ln_u_b = (const float*)d_in[24];
    const float* ln_i_g = (const float*)d_in[25];
    const float* ln_i_b = (const float*)d_in[26];
    const int* edge_ui  = (const int*)d_in[27];
    const int* edge_iu  = (const int*)d_in[28];
    const int* user_neg = (const int*)d_in[30];
    const int* item_neg = (const int*)d_in[31];

    float* out = (float*)d_out;
    // output layout: hu [NU*128] | hi [NI*128] | loss [1] | user_probs [NU]
    float* out_hu   = out;
    float* out_hi   = out + (size_t)NUU * 128;
    float* out_loss = out + 19200000;
    float* out_prob = out + 19200001;

    // workspace layout (~135 MB), all 16B-aligned
    float* hu0 = (float*)d_ws;               // fp32 proj output (enc input only)
    float* nu  = hu0 + (size_t)NUU * 128;
    float* ni  = nu + NUU;
    int* ip  = (int*)(ni + NII);
    int* rs  = ip;  ip += NROWS + 16;   // combined rowstart: items [0,NII], users [NII,NROWS]
    int* cur = ip;  ip += NROWS;        // combined degree/cursor
    int* el  = ip;  ip += 2 * NEDGE;    // combined edge list (absolute offsets via rs)
    int* pt  = ip;  ip += 160;          // scan partials (147 used)
    unsigned short* wsp = (unsigned short*)ip;        // 15 x (16384 hi + 16384 lo) bf16
    _Float16* hu16 = (_Float16*)(wsp + 15 * 32768);   // fp16 h (current layer)
    _Float16* hi16 = hu16 + (size_t)NUU * 128;
    _Float16* au16 = hi16 + (size_t)NII * 128;        // fp16 agg outputs
    _Float16* ai16 = au16 + (size_t)NUU * 128;

    const int* ui_src = edge_ui;           // users
    const int* ui_dst = edge_ui + NEDGE;   // items
    const int* iu_src = edge_iu;           // items
    const int* iu_dst = edge_iu + NEDGE;   // users

    const int GB_U = (NUU + 255) / 256, GB_I = (NII + 255) / 256;   // 391 / 196
    const int PB = (NROWS + 1023) / 1024;          // 147 scan blocks

    // weight pre-split (frag-ordered bf16 hi/lo planes), every launch
    WSrc ws7 = {{Wu_proj, Wi_proj, Wu_enc, Wl_ui, Wr_ui, Wl_iu, Wr_iu}};
    wsplit_k<<<(15 * 16384 + 255) / 256, 256, 0, stream>>>(ws7, wsp);
    unsigned short* wm[15];
    for (int m = 0; m < 15; ++m) wm[m] = wsp + (size_t)m * 32768;

    // projections user+item in one launch (+ fused row norms + fp16 copies);
    // item fp32 output is dead (only fp16 consumed downstream)
    GemmP pu_ = {x_user, wm[0], wm[0] + 16384, nullptr, nullptr, nullptr,
                 bu_proj, nullptr, nullptr, hu0, hu16, nu, NUU, 0, 0};
    GemmP pi_ = {x_item, wm[1], wm[1] + 16384, nullptr, nullptr, nullptr,
                 bi_proj, nullptr, nullptr, nullptr, hi16, ni, NII, 0, 0};
    gemm_dual<<<GB_U + GB_I, 256, 0, stream>>>(pu_, pi_, GB_U, nullptr, nullptr, nullptr, nullptr);
    // encoder + fused gumbel-hard head (writes only user_probs; fully fp32 path)
    GemmP pe_ = {hu0, wm[2], wm[2] + 16384, nullptr, nullptr, nullptr,
                 bu_enc, nullptr, nullptr, nullptr, nullptr, nullptr, NUU, 1, 0};
    gemm_dual<<<GB_U, 256, 0, stream>>>(pe_, pe_, GB_U, Wu_act, bu_act, u_user, out_prob);
    // structural loss (fp16 gathers from proj copies; must precede layer overwrites)
    hipMemsetAsync(out_loss, 0, 4, stream);
    loss_k<<<2048, 256, 0, stream>>>(hu16, hi16, nu, ni, ui_src, ui_dst, user_neg, item_neg, out_loss, NEDGE);
    // CSR build over combined row space (edge structure is layer-invariant)
    hipMemsetAsync(cur, 0, (size_t)NROWS * 4, stream);
    hist2_k<<<(2 * NEDGE + 255) / 256, 256, 0, stream>>>(ui_dst, iu_dst, cur);
    scan_part_k<<<PB, 256, 0, stream>>>(cur, pt, NROWS);
    scan_top_k<<<1, 256, 0, stream>>>(pt, PB);
    scan_final_k<<<PB, 256, 0, stream>>>(cur, pt, rs, NROWS, 2 * NEDGE);
    hipMemsetAsync(cur, 0, (size_t)NROWS * 4, stream);
    fill2_k<<<(2 * NEDGE + 255) / 256, 256, 0, stream>>>(ui_dst, ui_src, iu_dst, iu_src, rs, cur, el);

    // 3 hetero SAGE layers, fp16 h-chain: agg gathers h16 -> a16; GEMM reads
    // a16 (A1) + h16 (A2, fp16-exact split) and writes h16 in-place (l<2) or
    // fp32 d_out (l=2). No fp32 intermediates.
    for (int l = 0; l < 3; ++l) {
        int mode = (l < 2) ? 2 : 0;   // LN on hidden layers only
        agg_dual<<<NROWS / 4, 256, 0, stream>>>(hu16, hi16, rs, el, ai16, au16);
        GemmP li_ = {ai16, wm[3 + l], wm[3 + l] + 16384, hi16, wm[6 + l], wm[6 + l] + 16384,
                     b_ui + l * 128, ln_i_g + (l < 2 ? l : 0) * 128, ln_i_b + (l < 2 ? l : 0) * 128,
                     (l == 2) ? out_hi : nullptr, (l < 2) ? hi16 : nullptr, nullptr, NII, mode, 1};
        GemmP lu_ = {au16, wm[9 + l], wm[9 + l] + 16384, hu16, wm[12 + l], wm[12 + l] + 16384,
                     b_iu + l * 128, ln_u_g + (l < 2 ? l : 0) * 128, ln_u_b + (l < 2 ? l : 0) * 128,
                     (l == 2) ? out_hu : nullptr, (l < 2) ? hu16 : nullptr, nullptr, NUU, mode, 1};
        gemm_dual<<<GB_I + GB_U, 256, 0, stream>>>(li_, lu_, GB_I, nullptr, nullptr, nullptr, nullptr);
    }
}